// Round 11
// baseline (319.135 us; speedup 1.0000x reference)
//
#include <hip/hip_runtime.h>
#include <math.h>

#define EPS_F 1e-8f
#define NCH 4

__device__ __forceinline__ float frcp(float x) { return __builtin_amdgcn_rcpf(x); }

typedef __fp16 h2f __attribute__((ext_vector_type(2)));

__device__ __forceinline__ unsigned packh2(float x, float y) {
    h2f h = __builtin_amdgcn_cvt_pkrtz(x, y);   // v_cvt_pkrtz_f16_f32
    return __builtin_bit_cast(unsigned, h);
}
__device__ __forceinline__ void unpackh2(unsigned u, float& x, float& y) {
    h2f h = __builtin_bit_cast(h2f, u);
    x = (float)h.x; y = (float)h.y;
}

__global__ void __launch_bounds__(64) iou3d_init(double* acc) {
    if (threadIdx.x == 0) { acc[0] = 0.0; acc[1] = 0.0; }
}

// Build candidate vertices + sort keys for one element (reference-exact,
// validated rounds 3-10: absmax 0.0). Out-of-range i clamps to N-1; the
// epilogue masks its contribution to 0.
__device__ __forceinline__ void build(
    int i, int N,
    const float* __restrict__ pred_boxes, const float* __restrict__ gt_boxes,
    unsigned (&pl)[24], unsigned (&kk)[24],
    float& omx, float& omy, int& onv)
{
    int ic = i < N ? i : (N - 1);
    const float* b1 = pred_boxes + (size_t)ic * 7;
    const float* b2 = gt_boxes   + (size_t)ic * 8;

    float x1c = b1[0], y1c = b1[1], w1 = b1[3], h1 = b1[4], a1 = b1[6];
    float w2 = b2[3], h2v = b2[4];
    float s2v = b2[6], c2v = b2[7];
    float tx2 = b2[0] - x1c, ty2 = b2[1] - y1c;   // pred-center-relative frame

    float invn = rsqrtf(s2v * s2v + c2v * c2v);
    float cs2 = c2v * invn, sn2 = s2v * invn;
    const float INV2PI = 0.15915494309189535f;
    float sn1 = __builtin_amdgcn_sinf(a1 * INV2PI);
    float cs1 = __builtin_amdgcn_cosf(a1 * INV2PI);

    const float DX[4] = {0.5f, -0.5f, -0.5f, 0.5f};
    const float DY[4] = {0.5f,  0.5f, -0.5f, -0.5f};
    float c1x[4], c1y[4], c2x[4], c2y[4];
    #pragma unroll
    for (int k = 0; k < 4; ++k) {
        float cx = DX[k] * w1, cy = DY[k] * h1;
        c1x[k] = cx * cs1 - cy * sn1;
        c1y[k] = cx * sn1 + cy * cs1;
        float gx = DX[k] * w2, gy = DY[k] * h2v;
        c2x[k] = gx * cs2 - gy * sn2 + tx2;
        c2y[k] = gx * sn2 + gy * cs2 + ty2;
    }

    unsigned vmask = 0;
    float sx = 0.f, sy = 0.f;
    const float HB = 0.5f + 1e-6f;   // |p-0.5|<HB  <=>  -1e-6<p<1+1e-6

    // corner containment (reference-exact predicates), slots 0..7
    {
        float abx = c2x[1] - c2x[0], aby = c2y[1] - c2y[0];
        float adx = c2x[3] - c2x[0], ady = c2y[3] - c2y[0];
        float iab = frcp(abx * abx + aby * aby);
        float iad = frcp(adx * adx + ady * ady);
        #pragma unroll
        for (int k = 0; k < 4; ++k) {
            float amx = c1x[k] - c2x[0], amy = c1y[k] - c2y[0];
            float pab = (abx * amx + aby * amy) * iab;
            float pad = (adx * amx + ady * amy) * iad;
            bool ok = (fabsf(pab - 0.5f) < HB) && (fabsf(pad - 0.5f) < HB);
            pl[k] = packh2(c1x[k], c1y[k]);
            vmask |= ok ? (1u << k) : 0u;
            sx += ok ? c1x[k] : 0.f;
            sy += ok ? c1y[k] : 0.f;
        }
        abx = c1x[1] - c1x[0]; aby = c1y[1] - c1y[0];
        adx = c1x[3] - c1x[0]; ady = c1y[3] - c1y[0];
        iab = frcp(abx * abx + aby * aby);
        iad = frcp(adx * adx + ady * ady);
        #pragma unroll
        for (int k = 0; k < 4; ++k) {
            float amx = c2x[k] - c1x[0], amy = c2y[k] - c1y[0];
            float pab = (abx * amx + aby * amy) * iab;
            float pad = (adx * amx + ady * amy) * iad;
            bool ok = (fabsf(pab - 0.5f) < HB) && (fabsf(pad - 0.5f) < HB);
            pl[4 + k] = packh2(c2x[k], c2y[k]);
            vmask |= ok ? (1u << (4 + k)) : 0u;
            sx += ok ? c2x[k] : 0.f;
            sy += ok ? c2y[k] : 0.f;
        }
    }

    // 16 edge-pair points, slots 8..23 — REFERENCE-EXACT formulas
    // (reference's t is the NEGATED standard parameter; replicate, not fix)
    #pragma unroll
    for (int ii = 0; ii < 4; ++ii) {
        float ex1 = c1x[ii],       ey1 = c1y[ii];
        float ex2 = c1x[(ii+1)&3], ey2 = c1y[(ii+1)&3];
        #pragma unroll
        for (int jj = 0; jj < 4; ++jj) {
            float ex3 = c2x[jj],       ey3 = c2y[jj];
            float ex4 = c2x[(jj+1)&3], ey4 = c2y[(jj+1)&3];
            float num  = (ex2-ex1)*(ey3-ey4) - (ey2-ey1)*(ex3-ex4);
            float dent = (ex1-ex3)*(ey3-ey4) - (ey1-ey3)*(ex3-ex4);
            float denu = (ex1-ex3)*(ey1-ey2) - (ey1-ey3)*(ex1-ex2);
            float rn = frcp(num + EPS_F);
            float t = dent * rn;
            float u = -denu * rn;
            bool ok = (fabsf(t - 0.5f) < 0.5f) && (fabsf(u - 0.5f) < 0.5f) &&
                      (num != 0.f);
            int idx = 8 + ii*4 + jj;
            float px_ = ex1 + t * (ex2 - ex1);
            float py_ = ey1 + t * (ey2 - ey1);
            pl[idx] = packh2(px_, py_);
            vmask |= ok ? (1u << idx) : 0u;
            sx += ok ? px_ : 0.f;
            sy += ok ? py_ : 0.f;
        }
    }

    int nv = __popc(vmask);
    float rdn = frcp((float)(nv < 1 ? 1 : nv));
    float mx = sx * rdn, my = sy * rdn;

    // pseudo-angle (monotone in atan2) -> sortable u32, low 5 bits = index
    #pragma unroll
    for (int k = 0; k < 24; ++k) {
        float x_, y_;
        unpackh2(pl[k], x_, y_);
        float dx = x_ - mx, dy = y_ - my;
        float dd = fabsf(dx) + fabsf(dy);
        float tt = (dd > 0.f) ? dy * frcp(dd) : 0.f;
        float p  = (dx >= 0.f) ? tt : (copysignf(2.f, dy) - tt);
        int sb = __float_as_int(p);
        unsigned u = (unsigned)sb ^ (unsigned)((sb >> 31) | 0x80000000);
        bool v = (vmask >> k) & 1u;
        kk[k] = v ? ((u & 0xFFFFFFE0u) | (unsigned)k)
                  : (0xFFFFFFE0u | (unsigned)k);   // +inf region
    }

    omx = mx; omy = my; onv = nv;
}

// 4 elements per thread: four independent dependency chains interleaved
// through the sort + shoelace (dep distance 4 covers VALU latency within
// one wave). Generous register budget (launch_bounds min-waves=1 -> 512)
// so the allocator has ~2.3x headroom over the ~220-reg live set — the
// round-5/round-10 spill mode needs >=2x (measured).
__global__ void __launch_bounds__(256, 1) iou3d_main(
    const float* __restrict__ pred_iou,
    const float* __restrict__ pred_boxes,   // N x 7: x y z w l h yaw
    const float* __restrict__ gt_boxes,     // N x 8: x y z w l h sin cos
    const int*   __restrict__ mask,
    double* __restrict__ acc,
    int N)
{
    int tid = blockIdx.x * blockDim.x + threadIdx.x;
    int T   = gridDim.x * blockDim.x;   // chain c handles element tid + c*T

    unsigned pl[NCH][24], kk[NCH][24];
    float mxv[NCH], myv[NCH];
    int nvv[NCH];

    #pragma unroll
    for (int c = 0; c < NCH; ++c)
        build(tid + c * T, N, pred_boxes, gt_boxes,
              pl[c], kk[c], mxv[c], myv[c], nvv[c]);

    // Batcher odd-even mergesort (32-net pruned to slots <24; validated
    // rounds 3-10), NCH independent networks interleaved CE-by-CE
    #pragma unroll
    for (int pb = 1; pb < 32; pb <<= 1) {
      #pragma unroll
      for (int qb = pb; qb >= 1; qb >>= 1) {
        #pragma unroll
        for (int jb = qb % pb; jb + qb < 32; jb += 2 * qb) {
          #pragma unroll
          for (int ib = 0; ib < qb; ++ib) {
            int a = jb + ib, b = jb + ib + qb;
            if (b < 24 && (a / (2 * pb)) == (b / (2 * pb))) {
                #pragma unroll
                for (int c = 0; c < NCH; ++c) {
                    unsigned ka = kk[c][a], kb2 = kk[c][b];
                    bool sw = kb2 < ka;
                    unsigned mn  = ka < kb2 ? ka : kb2;    // v_min_u32
                    unsigned mxk = ka < kb2 ? kb2 : ka;    // v_max_u32
                    unsigned pa = pl[c][a], pb2 = pl[c][b];
                    unsigned qa = sw ? pb2 : pa;
                    unsigned qb2 = sw ? pa : pb2;
                    kk[c][a] = mn; kk[c][b] = mxk;
                    pl[c][a] = qa; pl[c][b] = qb2;
                }
            }
          }
        }
      }
    }

    // shoelace over sorted centroid-relative vertices, chains interleaved;
    // positions >= nv padded with first sorted vertex (reference-exact)
    float fx[NCH], fy[NCH], prx[NCH], pry[NCH], area2[NCH];
    #pragma unroll
    for (int c = 0; c < NCH; ++c) {
        unpackh2(pl[c][0], fx[c], fy[c]);
        fx[c] -= mxv[c]; fy[c] -= myv[c];
        prx[c] = fx[c]; pry[c] = fy[c]; area2[c] = 0.f;
    }
    #pragma unroll
    for (int k = 1; k < 24; ++k) {
        #pragma unroll
        for (int c = 0; c < NCH; ++c) {
            float x_, y_;
            unpackh2(pl[c][k], x_, y_);
            bool use = (k < nvv[c]);
            float cx_ = use ? (x_ - mxv[c]) : fx[c];
            float cy_ = use ? (y_ - myv[c]) : fy[c];
            area2[c] += prx[c] * cy_ - pry[c] * cx_;
            prx[c] = cx_; pry[c] = cy_;
        }
    }

    // epilogue: reload tail quantities (L2-resident; validated round 10)
    float wabs = 0.f, mval = 0.f;
    #pragma unroll
    for (int c = 0; c < NCH; ++c) {
        int i = tid + c * T;
        int ic = i < N ? i : (N - 1);
        const float* b1 = pred_boxes + (size_t)ic * 7;
        const float* b2 = gt_boxes   + (size_t)ic * 8;
        float inter2d = fabsf(area2[c]) * 0.5f;
        float z1 = b1[2], d1 = b1[5], z2 = b2[2], d2 = b2[5];
        float zmax = fminf(z1 + d1 * 0.5f, z2 + d2 * 0.5f);
        float zmin = fmaxf(z1 - d1 * 0.5f, z2 - d2 * 0.5f);
        float inter3d = inter2d * fmaxf(zmax - zmin, 0.f);
        float vol1 = b1[3] * b1[4] * d1;
        float vol2 = b2[3] * b2[4] * d2;
        float iou = inter3d / (vol1 + vol2 - inter3d);
        float target = iou * 2.f - 1.f;
        float m = (i < N) ? (float)mask[ic] : 0.f;
        wabs += fabsf(pred_iou[ic] - target) * m;
        mval += m;
    }

    // block reduction: wave shfl-xor, then LDS across 4 waves, then atomic
    #pragma unroll
    for (int off = 32; off > 0; off >>= 1) {
        wabs += __shfl_xor(wabs, off);
        mval += __shfl_xor(mval, off);
    }
    __shared__ float sw_[4], sm_[4];
    int lane = threadIdx.x & 63;
    int wid  = threadIdx.x >> 6;
    if (lane == 0) { sw_[wid] = wabs; sm_[wid] = mval; }
    __syncthreads();
    if (threadIdx.x == 0) {
        float tw = sw_[0] + sw_[1] + sw_[2] + sw_[3];
        float tm = sm_[0] + sm_[1] + sm_[2] + sm_[3];
        atomicAdd(&acc[0], (double)tw);
        atomicAdd(&acc[1], (double)tm);
    }
}

__global__ void __launch_bounds__(64) iou3d_final(const double* __restrict__ acc,
                                                  float* __restrict__ out) {
    if (threadIdx.x == 0 && blockIdx.x == 0) {
        double s  = acc[0];
        double dm = acc[1];
        double denom = dm > 1e-4 ? dm : 1e-4;
        out[0] = (float)(s / denom);   // LOSS_WEIGHT = 1
    }
}

extern "C" void kernel_launch(void* const* d_in, const int* in_sizes, int n_in,
                              void* d_out, int out_size, void* d_ws, size_t ws_size,
                              hipStream_t stream) {
    const float* pred_iou   = (const float*)d_in[0];
    const float* pred_boxes = (const float*)d_in[1];
    const float* gt_boxes   = (const float*)d_in[2];
    const int*   mask       = (const int*)d_in[3];
    float* out = (float*)d_out;
    double* acc = (double*)d_ws;

    int N = in_sizes[0];
    int blocks = (N + 256 * NCH - 1) / (256 * NCH);   // 4 elements per thread

    iou3d_init<<<1, 64, 0, stream>>>(acc);
    iou3d_main<<<blocks, 256, 0, stream>>>(pred_iou, pred_boxes, gt_boxes, mask, acc, N);
    iou3d_final<<<1, 64, 0, stream>>>(acc, out);
}

// Round 12
// 60.396 us; speedup vs baseline: 5.2841x; 5.2841x over previous
//
#include <hip/hip_runtime.h>
#include <math.h>

#define EPS_F 1e-8f

__device__ __forceinline__ float frcp(float x) { return __builtin_amdgcn_rcpf(x); }

typedef __fp16 h2f __attribute__((ext_vector_type(2)));

__device__ __forceinline__ unsigned packh2(float x, float y) {
    h2f h = __builtin_amdgcn_cvt_pkrtz(x, y);   // v_cvt_pkrtz_f16_f32
    return __builtin_bit_cast(unsigned, h);
}
__device__ __forceinline__ void unpackh2(unsigned u, float& x, float& y) {
    h2f h = __builtin_bit_cast(h2f, u);
    x = (float)h.x; y = (float)h.y;
}

__global__ void __launch_bounds__(64) iou3d_init(double* acc, unsigned* cnt) {
    if (threadIdx.x == 0) { acc[0] = 0.0; acc[1] = 0.0; cnt[0] = 0u; }
}

// ---- compaction: indices of mask!=0, one atomic per block ----
__global__ void __launch_bounds__(256) iou3d_compact(
    const int* __restrict__ mask, unsigned* __restrict__ cnt,
    unsigned* __restrict__ cidx, int N)
{
    int i = blockIdx.x * 256 + threadIdx.x;
    bool act = (i < N) && (mask[i] != 0);
    unsigned long long bal = __ballot(act);
    int lane = threadIdx.x & 63, wid = threadIdx.x >> 6;
    int rank = __popcll(bal & ((1ull << lane) - 1ull));
    int wtot = __popcll(bal);
    __shared__ unsigned woff[4];
    __shared__ unsigned base;
    if (lane == 0) woff[wid] = (unsigned)wtot;
    __syncthreads();
    if (threadIdx.x == 0) {
        unsigned s0 = woff[0], s1 = woff[1], s2 = woff[2], s3 = woff[3];
        base = atomicAdd(cnt, s0 + s1 + s2 + s3);
        woff[0] = 0; woff[1] = s0; woff[2] = s0 + s1; woff[3] = s0 + s1 + s2;
    }
    __syncthreads();
    if (act) cidx[base + woff[wid] + (unsigned)rank] = (unsigned)i;
}

// ---- per-element candidate construction (reference-exact; rounds 3-11) ----
__device__ __forceinline__ void build(
    int ic,
    const float* __restrict__ pred_boxes, const float* __restrict__ gt_boxes,
    unsigned (&pl)[24], unsigned (&kk)[24],
    float& omx, float& omy, int& onv)
{
    const float* b1 = pred_boxes + (size_t)ic * 7;
    const float* b2 = gt_boxes   + (size_t)ic * 8;

    float x1c = b1[0], y1c = b1[1], w1 = b1[3], h1 = b1[4], a1 = b1[6];
    float w2 = b2[3], h2v = b2[4];
    float s2v = b2[6], c2v = b2[7];
    float tx2 = b2[0] - x1c, ty2 = b2[1] - y1c;   // pred-center-relative frame

    float invn = rsqrtf(s2v * s2v + c2v * c2v);
    float cs2 = c2v * invn, sn2 = s2v * invn;
    const float INV2PI = 0.15915494309189535f;
    float sn1 = __builtin_amdgcn_sinf(a1 * INV2PI);
    float cs1 = __builtin_amdgcn_cosf(a1 * INV2PI);

    const float DX[4] = {0.5f, -0.5f, -0.5f, 0.5f};
    const float DY[4] = {0.5f,  0.5f, -0.5f, -0.5f};
    float c1x[4], c1y[4], c2x[4], c2y[4];
    #pragma unroll
    for (int k = 0; k < 4; ++k) {
        float cx = DX[k] * w1, cy = DY[k] * h1;
        c1x[k] = cx * cs1 - cy * sn1;
        c1y[k] = cx * sn1 + cy * cs1;
        float gx = DX[k] * w2, gy = DY[k] * h2v;
        c2x[k] = gx * cs2 - gy * sn2 + tx2;
        c2y[k] = gx * sn2 + gy * cs2 + ty2;
    }

    unsigned vmask = 0;
    float sx = 0.f, sy = 0.f;
    const float HB = 0.5f + 1e-6f;   // |p-0.5|<HB  <=>  -1e-6<p<1+1e-6

    {
        float abx = c2x[1] - c2x[0], aby = c2y[1] - c2y[0];
        float adx = c2x[3] - c2x[0], ady = c2y[3] - c2y[0];
        float iab = frcp(abx * abx + aby * aby);
        float iad = frcp(adx * adx + ady * ady);
        #pragma unroll
        for (int k = 0; k < 4; ++k) {
            float amx = c1x[k] - c2x[0], amy = c1y[k] - c2y[0];
            float pab = (abx * amx + aby * amy) * iab;
            float pad = (adx * amx + ady * amy) * iad;
            bool ok = (fabsf(pab - 0.5f) < HB) && (fabsf(pad - 0.5f) < HB);
            pl[k] = packh2(c1x[k], c1y[k]);
            vmask |= ok ? (1u << k) : 0u;
            sx += ok ? c1x[k] : 0.f;
            sy += ok ? c1y[k] : 0.f;
        }
        abx = c1x[1] - c1x[0]; aby = c1y[1] - c1y[0];
        adx = c1x[3] - c1x[0]; ady = c1y[3] - c1y[0];
        iab = frcp(abx * abx + aby * aby);
        iad = frcp(adx * adx + ady * ady);
        #pragma unroll
        for (int k = 0; k < 4; ++k) {
            float amx = c2x[k] - c1x[0], amy = c2y[k] - c1y[0];
            float pab = (abx * amx + aby * amy) * iab;
            float pad = (adx * amx + ady * amy) * iad;
            bool ok = (fabsf(pab - 0.5f) < HB) && (fabsf(pad - 0.5f) < HB);
            pl[4 + k] = packh2(c2x[k], c2y[k]);
            vmask |= ok ? (1u << (4 + k)) : 0u;
            sx += ok ? c2x[k] : 0.f;
            sy += ok ? c2y[k] : 0.f;
        }
    }

    // 16 edge-pair points — REFERENCE-EXACT formulas (t is the NEGATED
    // standard parameter; replicate, not fix)
    #pragma unroll
    for (int ii = 0; ii < 4; ++ii) {
        float ex1 = c1x[ii],       ey1 = c1y[ii];
        float ex2 = c1x[(ii+1)&3], ey2 = c1y[(ii+1)&3];
        #pragma unroll
        for (int jj = 0; jj < 4; ++jj) {
            float ex3 = c2x[jj],       ey3 = c2y[jj];
            float ex4 = c2x[(jj+1)&3], ey4 = c2y[(jj+1)&3];
            float num  = (ex2-ex1)*(ey3-ey4) - (ey2-ey1)*(ex3-ex4);
            float dent = (ex1-ex3)*(ey3-ey4) - (ey1-ey3)*(ex3-ex4);
            float denu = (ex1-ex3)*(ey1-ey2) - (ey1-ey3)*(ex1-ex2);
            float rn = frcp(num + EPS_F);
            float t = dent * rn;
            float u = -denu * rn;
            bool ok = (fabsf(t - 0.5f) < 0.5f) && (fabsf(u - 0.5f) < 0.5f) &&
                      (num != 0.f);
            int idx = 8 + ii*4 + jj;
            float px_ = ex1 + t * (ex2 - ex1);
            float py_ = ey1 + t * (ey2 - ey1);
            pl[idx] = packh2(px_, py_);
            vmask |= ok ? (1u << idx) : 0u;
            sx += ok ? px_ : 0.f;
            sy += ok ? py_ : 0.f;
        }
    }

    int nv = __popc(vmask);
    float rdn = frcp((float)(nv < 1 ? 1 : nv));
    float mx = sx * rdn, my = sy * rdn;

    #pragma unroll
    for (int k = 0; k < 24; ++k) {
        float x_, y_;
        unpackh2(pl[k], x_, y_);
        float dx = x_ - mx, dy = y_ - my;
        float dd = fabsf(dx) + fabsf(dy);
        float tt = (dd > 0.f) ? dy * frcp(dd) : 0.f;
        float p  = (dx >= 0.f) ? tt : (copysignf(2.f, dy) - tt);
        int sb = __float_as_int(p);
        unsigned u = (unsigned)sb ^ (unsigned)((sb >> 31) | 0x80000000);
        bool v = (vmask >> k) & 1u;
        kk[k] = v ? ((u & 0xFFFFFFE0u) | (unsigned)k)
                  : (0xFFFFFFE0u | (unsigned)k);   // +inf region
    }

    omx = mx; omy = my; onv = nv;
}

// ---- r9 pair core: build x2, interleaved sort + shoelace + epilogue ----
__device__ __forceinline__ void pair_core(
    int icA, int icB, float mA, float mB,
    const float* __restrict__ pred_iou,
    const float* __restrict__ pred_boxes,
    const float* __restrict__ gt_boxes,
    float& wabs, float& mval)
{
    unsigned kkA[24], plA[24], kkB[24], plB[24];
    float mxA, myA, mxB, myB;
    int nvA, nvB;
    build(icA, pred_boxes, gt_boxes, plA, kkA, mxA, myA, nvA);
    build(icB, pred_boxes, gt_boxes, plB, kkB, mxB, myB, nvB);

    // Batcher odd-even mergesort (32-net pruned to slots <24; validated
    // rounds 3-11), two networks interleaved CE-by-CE for ILP
    #pragma unroll
    for (int pb = 1; pb < 32; pb <<= 1) {
      #pragma unroll
      for (int qb = pb; qb >= 1; qb >>= 1) {
        #pragma unroll
        for (int jb = qb % pb; jb + qb < 32; jb += 2 * qb) {
          #pragma unroll
          for (int ib = 0; ib < qb; ++ib) {
            int a = jb + ib, b = jb + ib + qb;
            if (b < 24 && (a / (2 * pb)) == (b / (2 * pb))) {
                {
                    unsigned ka = kkA[a], kb2 = kkA[b];
                    bool sw = kb2 < ka;
                    unsigned mn  = ka < kb2 ? ka : kb2;
                    unsigned mxk = ka < kb2 ? kb2 : ka;
                    unsigned pa = plA[a], pb2 = plA[b];
                    kkA[a] = mn; kkA[b] = mxk;
                    plA[a] = sw ? pb2 : pa; plA[b] = sw ? pa : pb2;
                }
                {
                    unsigned ka = kkB[a], kb2 = kkB[b];
                    bool sw = kb2 < ka;
                    unsigned mn  = ka < kb2 ? ka : kb2;
                    unsigned mxk = ka < kb2 ? kb2 : ka;
                    unsigned pa = plB[a], pb2 = plB[b];
                    kkB[a] = mn; kkB[b] = mxk;
                    plB[a] = sw ? pb2 : pa; plB[b] = sw ? pa : pb2;
                }
            }
          }
        }
      }
    }

    // shoelace over sorted centroid-relative vertices, A/B interleaved;
    // positions >= nv padded with first sorted vertex (reference-exact)
    float fxA, fyA, fxB, fyB;
    unpackh2(plA[0], fxA, fyA); fxA -= mxA; fyA -= myA;
    unpackh2(plB[0], fxB, fyB); fxB -= mxB; fyB -= myB;
    float prxA = fxA, pryA = fyA, areaA = 0.f;
    float prxB = fxB, pryB = fyB, areaB = 0.f;
    #pragma unroll
    for (int k = 1; k < 24; ++k) {
        float xA, yA, xB, yB;
        unpackh2(plA[k], xA, yA);
        unpackh2(plB[k], xB, yB);
        bool useA = (k < nvA), useB = (k < nvB);
        float cxA = useA ? (xA - mxA) : fxA;
        float cyA = useA ? (yA - myA) : fyA;
        float cxB = useB ? (xB - mxB) : fxB;
        float cyB = useB ? (yB - myB) : fyB;
        areaA += prxA * cyA - pryA * cxA;
        areaB += prxB * cyB - pryB * cxB;
        prxA = cxA; pryA = cyA;
        prxB = cxB; pryB = cyB;
    }

    const float* b1A = pred_boxes + (size_t)icA * 7;
    const float* b2A = gt_boxes   + (size_t)icA * 8;
    const float* b1B = pred_boxes + (size_t)icB * 7;
    const float* b2B = gt_boxes   + (size_t)icB * 8;

    float i2A = fabsf(areaA) * 0.5f;
    float i2B = fabsf(areaB) * 0.5f;
    float zA = fmaxf(fminf(b1A[2] + b1A[5]*0.5f, b2A[2] + b2A[5]*0.5f)
                   - fmaxf(b1A[2] - b1A[5]*0.5f, b2A[2] - b2A[5]*0.5f), 0.f);
    float zB = fmaxf(fminf(b1B[2] + b1B[5]*0.5f, b2B[2] + b2B[5]*0.5f)
                   - fmaxf(b1B[2] - b1B[5]*0.5f, b2B[2] - b2B[5]*0.5f), 0.f);
    float i3A = i2A * zA, i3B = i2B * zB;
    float vsA = b1A[3]*b1A[4]*b1A[5] + b2A[3]*b2A[4]*b2A[5];
    float vsB = b1B[3]*b1B[4]*b1B[5] + b2B[3]*b2B[4]*b2B[5];
    float iouA = i3A / (vsA - i3A);
    float iouB = i3B / (vsB - i3B);
    wabs = fabsf(pred_iou[icA] - (iouA * 2.f - 1.f)) * mA
         + fabsf(pred_iou[icB] - (iouB * 2.f - 1.f)) * mB;
    mval = mA + mB;
}

__device__ __forceinline__ void block_reduce(float wabs, float mval, double* acc) {
    #pragma unroll
    for (int off = 32; off > 0; off >>= 1) {
        wabs += __shfl_xor(wabs, off);
        mval += __shfl_xor(mval, off);
    }
    __shared__ float sw_[4], sm_[4];
    int lane = threadIdx.x & 63;
    int wid  = threadIdx.x >> 6;
    if (lane == 0) { sw_[wid] = wabs; sm_[wid] = mval; }
    __syncthreads();
    if (threadIdx.x == 0) {
        atomicAdd(&acc[0], (double)(sw_[0] + sw_[1] + sw_[2] + sw_[3]));
        atomicAdd(&acc[1], (double)(sm_[0] + sm_[1] + sm_[2] + sm_[3]));
    }
}

// compacted main: 2 consecutive compacted elements per thread;
// whole-block early exit before any barrier (graph-safe)
__global__ void __launch_bounds__(256, 2) iou3d_main_c(
    const float* __restrict__ pred_iou,
    const float* __restrict__ pred_boxes,
    const float* __restrict__ gt_boxes,
    const int*   __restrict__ mask,
    const unsigned* __restrict__ cnt,
    const unsigned* __restrict__ cidx,
    double* __restrict__ acc)
{
    int cN = (int)cnt[0];
    if ((int)blockIdx.x * 512 >= cN) return;   // uniform: whole block retires

    int tid = blockIdx.x * blockDim.x + threadIdx.x;
    int jA = 2 * tid, jB = 2 * tid + 1;
    int jcA = jA < cN ? jA : (cN - 1);
    int jcB = jB < cN ? jB : (cN - 1);
    int icA = (int)cidx[jcA];
    int icB = (int)cidx[jcB];
    float mA = (jA < cN) ? (float)mask[icA] : 0.f;
    float mB = (jB < cN) ? (float)mask[icB] : 0.f;

    float wabs, mval;
    pair_core(icA, icB, mA, mB, pred_iou, pred_boxes, gt_boxes, wabs, mval);
    block_reduce(wabs, mval, acc);
}

// fallback (ws too small): verbatim round-9 path
__global__ void __launch_bounds__(256, 2) iou3d_main_nc(
    const float* __restrict__ pred_iou,
    const float* __restrict__ pred_boxes,
    const float* __restrict__ gt_boxes,
    const int*   __restrict__ mask,
    double* __restrict__ acc,
    int N)
{
    int tid = blockIdx.x * blockDim.x + threadIdx.x;
    int iA = 2 * tid, iB = 2 * tid + 1;
    int icA = iA < N ? iA : (N - 1);
    int icB = iB < N ? iB : (N - 1);
    float mA = (iA < N) ? (float)mask[icA] : 0.f;
    float mB = (iB < N) ? (float)mask[icB] : 0.f;

    float wabs, mval;
    pair_core(icA, icB, mA, mB, pred_iou, pred_boxes, gt_boxes, wabs, mval);
    block_reduce(wabs, mval, acc);
}

__global__ void __launch_bounds__(64) iou3d_final(const double* __restrict__ acc,
                                                  float* __restrict__ out) {
    if (threadIdx.x == 0 && blockIdx.x == 0) {
        double s  = acc[0];
        double dm = acc[1];
        double denom = dm > 1e-4 ? dm : 1e-4;
        out[0] = (float)(s / denom);   // LOSS_WEIGHT = 1
    }
}

extern "C" void kernel_launch(void* const* d_in, const int* in_sizes, int n_in,
                              void* d_out, int out_size, void* d_ws, size_t ws_size,
                              hipStream_t stream) {
    const float* pred_iou   = (const float*)d_in[0];
    const float* pred_boxes = (const float*)d_in[1];
    const float* gt_boxes   = (const float*)d_in[2];
    const int*   mask       = (const int*)d_in[3];
    float* out = (float*)d_out;

    double*   acc  = (double*)d_ws;                       // 16 B
    unsigned* cnt  = (unsigned*)((char*)d_ws + 16);       // 4 B
    unsigned* cidx = (unsigned*)((char*)d_ws + 64);       // N*4 B

    int N = in_sizes[0];
    size_t need = 64 + (size_t)N * 4;

    iou3d_init<<<1, 64, 0, stream>>>(acc, cnt);
    if (ws_size >= need) {
        iou3d_compact<<<(N + 255) / 256, 256, 0, stream>>>(mask, cnt, cidx, N);
        iou3d_main_c<<<(N + 511) / 512, 256, 0, stream>>>(
            pred_iou, pred_boxes, gt_boxes, mask, cnt, cidx, acc);
    } else {
        iou3d_main_nc<<<(N + 511) / 512, 256, 0, stream>>>(
            pred_iou, pred_boxes, gt_boxes, mask, acc, N);
    }
    iou3d_final<<<1, 64, 0, stream>>>(acc, out);
}

// Round 13
// 44.820 us; speedup vs baseline: 7.1204x; 1.3475x over previous
//
#include <hip/hip_runtime.h>
#include <math.h>

#define EPS_F 1e-8f

__device__ __forceinline__ float frcp(float x) { return __builtin_amdgcn_rcpf(x); }

typedef __fp16 h2f __attribute__((ext_vector_type(2)));

__device__ __forceinline__ unsigned packh2(float x, float y) {
    h2f h = __builtin_amdgcn_cvt_pkrtz(x, y);   // v_cvt_pkrtz_f16_f32
    return __builtin_bit_cast(unsigned, h);
}
__device__ __forceinline__ void unpackh2(unsigned u, float& x, float& y) {
    h2f h = __builtin_bit_cast(h2f, u);
    x = (float)h.x; y = (float)h.y;
}

// (key30 << 32) | payload as a POSITIVE FINITE double: bit63=0 and bit62=0
// (key30 < 2^30) -> exponent field never all-ones -> no NaN/Inf. For positive
// finite doubles IEEE order == bit-pattern order, so v_min_f64/v_max_f64
// compare key and carry the payload in one shot (2-instruction CE).
__device__ __forceinline__ double mkkey(unsigned key30, unsigned payload) {
    unsigned long long u = ((unsigned long long)key30 << 32) | (unsigned long long)payload;
    return __builtin_bit_cast(double, u);
}
__device__ __forceinline__ unsigned keypl(double d) {
    return (unsigned)__builtin_bit_cast(unsigned long long, d);
}

__global__ void __launch_bounds__(64) iou3d_init(double* acc) {
    if (threadIdx.x == 0) { acc[0] = 0.0; acc[1] = 0.0; }
}

// ---- per-element candidate construction (reference-exact; rounds 3-12) ----
__device__ __forceinline__ void build(
    int ic,
    const float* __restrict__ pred_boxes, const float* __restrict__ gt_boxes,
    double (&kd)[24], float& omx, float& omy, int& onv)
{
    const float* b1 = pred_boxes + (size_t)ic * 7;
    const float* b2 = gt_boxes   + (size_t)ic * 8;

    float x1c = b1[0], y1c = b1[1], w1 = b1[3], h1 = b1[4], a1 = b1[6];
    float w2 = b2[3], h2v = b2[4];
    float s2v = b2[6], c2v = b2[7];
    float tx2 = b2[0] - x1c, ty2 = b2[1] - y1c;   // pred-center-relative frame

    float invn = rsqrtf(s2v * s2v + c2v * c2v);
    float cs2 = c2v * invn, sn2 = s2v * invn;
    const float INV2PI = 0.15915494309189535f;
    float sn1 = __builtin_amdgcn_sinf(a1 * INV2PI);
    float cs1 = __builtin_amdgcn_cosf(a1 * INV2PI);

    const float DX[4] = {0.5f, -0.5f, -0.5f, 0.5f};
    const float DY[4] = {0.5f,  0.5f, -0.5f, -0.5f};
    float c1x[4], c1y[4], c2x[4], c2y[4];
    #pragma unroll
    for (int k = 0; k < 4; ++k) {
        float cx = DX[k] * w1, cy = DY[k] * h1;
        c1x[k] = cx * cs1 - cy * sn1;
        c1y[k] = cx * sn1 + cy * cs1;
        float gx = DX[k] * w2, gy = DY[k] * h2v;
        c2x[k] = gx * cs2 - gy * sn2 + tx2;
        c2y[k] = gx * sn2 + gy * cs2 + ty2;
    }

    unsigned pl[24];
    unsigned vmask = 0;
    float sx = 0.f, sy = 0.f;
    const float HB = 0.5f + 1e-6f;   // |p-0.5|<HB  <=>  -1e-6<p<1+1e-6

    {
        float abx = c2x[1] - c2x[0], aby = c2y[1] - c2y[0];
        float adx = c2x[3] - c2x[0], ady = c2y[3] - c2y[0];
        float iab = frcp(abx * abx + aby * aby);
        float iad = frcp(adx * adx + ady * ady);
        #pragma unroll
        for (int k = 0; k < 4; ++k) {
            float amx = c1x[k] - c2x[0], amy = c1y[k] - c2y[0];
            float pab = (abx * amx + aby * amy) * iab;
            float pad = (adx * amx + ady * amy) * iad;
            bool ok = (fabsf(pab - 0.5f) < HB) && (fabsf(pad - 0.5f) < HB);
            pl[k] = packh2(c1x[k], c1y[k]);
            vmask |= ok ? (1u << k) : 0u;
            sx += ok ? c1x[k] : 0.f;
            sy += ok ? c1y[k] : 0.f;
        }
        abx = c1x[1] - c1x[0]; aby = c1y[1] - c1y[0];
        adx = c1x[3] - c1x[0]; ady = c1y[3] - c1y[0];
        iab = frcp(abx * abx + aby * aby);
        iad = frcp(adx * adx + ady * ady);
        #pragma unroll
        for (int k = 0; k < 4; ++k) {
            float amx = c2x[k] - c1x[0], amy = c2y[k] - c1y[0];
            float pab = (abx * amx + aby * amy) * iab;
            float pad = (adx * amx + ady * amy) * iad;
            bool ok = (fabsf(pab - 0.5f) < HB) && (fabsf(pad - 0.5f) < HB);
            pl[4 + k] = packh2(c2x[k], c2y[k]);
            vmask |= ok ? (1u << (4 + k)) : 0u;
            sx += ok ? c2x[k] : 0.f;
            sy += ok ? c2y[k] : 0.f;
        }
    }

    // 16 edge-pair points — REFERENCE-EXACT formulas (t is the NEGATED
    // standard parameter; replicate, not fix)
    #pragma unroll
    for (int ii = 0; ii < 4; ++ii) {
        float ex1 = c1x[ii],       ey1 = c1y[ii];
        float ex2 = c1x[(ii+1)&3], ey2 = c1y[(ii+1)&3];
        #pragma unroll
        for (int jj = 0; jj < 4; ++jj) {
            float ex3 = c2x[jj],       ey3 = c2y[jj];
            float ex4 = c2x[(jj+1)&3], ey4 = c2y[(jj+1)&3];
            float num  = (ex2-ex1)*(ey3-ey4) - (ey2-ey1)*(ex3-ex4);
            float dent = (ex1-ex3)*(ey3-ey4) - (ey1-ey3)*(ex3-ex4);
            float denu = (ex1-ex3)*(ey1-ey2) - (ey1-ey3)*(ex1-ex2);
            float rn = frcp(num + EPS_F);
            float t = dent * rn;
            float u = -denu * rn;
            bool ok = (fabsf(t - 0.5f) < 0.5f) && (fabsf(u - 0.5f) < 0.5f) &&
                      (num != 0.f);
            int idx = 8 + ii*4 + jj;
            float px_ = ex1 + t * (ex2 - ex1);
            float py_ = ey1 + t * (ey2 - ey1);
            pl[idx] = packh2(px_, py_);
            vmask |= ok ? (1u << idx) : 0u;
            sx += ok ? px_ : 0.f;
            sy += ok ? py_ : 0.f;
        }
    }

    int nv = __popc(vmask);
    float rdn = frcp((float)(nv < 1 ? 1 : nv));
    float mx = sx * rdn, my = sy * rdn;

    // pseudo-angle (monotone in atan2) -> 30-bit sortable key; payload (f16x2
    // coords) fused into the low 32 bits of a positive-finite double.
    // valid keys <= 0x30000000 < invalid marker 0x3FFFFFFF (sorts last).
    #pragma unroll
    for (int k = 0; k < 24; ++k) {
        float x_, y_;
        unpackh2(pl[k], x_, y_);
        float dx = x_ - mx, dy = y_ - my;
        float dd = fabsf(dx) + fabsf(dy);
        float tt = (dd > 0.f) ? dy * frcp(dd) : 0.f;
        float p  = (dx >= 0.f) ? tt : (copysignf(2.f, dy) - tt);
        int sb = __float_as_int(p);
        unsigned u = (unsigned)sb ^ (unsigned)((sb >> 31) | 0x80000000);
        bool v = (vmask >> k) & 1u;
        unsigned key30 = v ? (u >> 2) : 0x3FFFFFFFu;
        kd[k] = mkkey(key30, pl[k]);
    }

    omx = mx; omy = my; onv = nv;
}

// ---- pair core: build x2, f64-CE interleaved sort + shoelace + epilogue ----
__device__ __forceinline__ void pair_core(
    int icA, int icB, float mA, float mB,
    const float* __restrict__ pred_iou,
    const float* __restrict__ pred_boxes,
    const float* __restrict__ gt_boxes,
    float& wabs, float& mval)
{
    double kdA[24], kdB[24];
    float mxA, myA, mxB, myB;
    int nvA, nvB;
    build(icA, pred_boxes, gt_boxes, kdA, mxA, myA, nvA);
    build(icB, pred_boxes, gt_boxes, kdB, mxB, myB, nvB);

    // Batcher odd-even mergesort (32-net pruned to slots <24; validated
    // rounds 3-12). CE = v_min_f64 + v_max_f64 (key+payload in one word),
    // two independent networks interleaved for ILP.
    #pragma unroll
    for (int pb = 1; pb < 32; pb <<= 1) {
      #pragma unroll
      for (int qb = pb; qb >= 1; qb >>= 1) {
        #pragma unroll
        for (int jb = qb % pb; jb + qb < 32; jb += 2 * qb) {
          #pragma unroll
          for (int ib = 0; ib < qb; ++ib) {
            int a = jb + ib, b = jb + ib + qb;
            if (b < 24 && (a / (2 * pb)) == (b / (2 * pb))) {
                double a0 = kdA[a], b0 = kdA[b];
                kdA[a] = fmin(a0, b0);
                kdA[b] = fmax(a0, b0);
                double a1 = kdB[a], b1 = kdB[b];
                kdB[a] = fmin(a1, b1);
                kdB[b] = fmax(a1, b1);
            }
          }
        }
      }
    }

    // shoelace over sorted centroid-relative vertices, A/B interleaved;
    // positions >= nv padded with first sorted vertex (reference-exact)
    float fxA, fyA, fxB, fyB;
    unpackh2(keypl(kdA[0]), fxA, fyA); fxA -= mxA; fyA -= myA;
    unpackh2(keypl(kdB[0]), fxB, fyB); fxB -= mxB; fyB -= myB;
    float prxA = fxA, pryA = fyA, areaA = 0.f;
    float prxB = fxB, pryB = fyB, areaB = 0.f;
    #pragma unroll
    for (int k = 1; k < 24; ++k) {
        float xA, yA, xB, yB;
        unpackh2(keypl(kdA[k]), xA, yA);
        unpackh2(keypl(kdB[k]), xB, yB);
        bool useA = (k < nvA), useB = (k < nvB);
        float cxA = useA ? (xA - mxA) : fxA;
        float cyA = useA ? (yA - myA) : fyA;
        float cxB = useB ? (xB - mxB) : fxB;
        float cyB = useB ? (yB - myB) : fyB;
        areaA += prxA * cyA - pryA * cxA;
        areaB += prxB * cyB - pryB * cxB;
        prxA = cxA; pryA = cyA;
        prxB = cxB; pryB = cyB;
    }

    const float* b1A = pred_boxes + (size_t)icA * 7;
    const float* b2A = gt_boxes   + (size_t)icA * 8;
    const float* b1B = pred_boxes + (size_t)icB * 7;
    const float* b2B = gt_boxes   + (size_t)icB * 8;

    float i2A = fabsf(areaA) * 0.5f;
    float i2B = fabsf(areaB) * 0.5f;
    float zA = fmaxf(fminf(b1A[2] + b1A[5]*0.5f, b2A[2] + b2A[5]*0.5f)
                   - fmaxf(b1A[2] - b1A[5]*0.5f, b2A[2] - b2A[5]*0.5f), 0.f);
    float zB = fmaxf(fminf(b1B[2] + b1B[5]*0.5f, b2B[2] + b2B[5]*0.5f)
                   - fmaxf(b1B[2] - b1B[5]*0.5f, b2B[2] - b2B[5]*0.5f), 0.f);
    float i3A = i2A * zA, i3B = i2B * zB;
    float vsA = b1A[3]*b1A[4]*b1A[5] + b2A[3]*b2A[4]*b2A[5];
    float vsB = b1B[3]*b1B[4]*b1B[5] + b2B[3]*b2B[4]*b2B[5];
    float iouA = i3A / (vsA - i3A);
    float iouB = i3B / (vsB - i3B);
    wabs = fabsf(pred_iou[icA] - (iouA * 2.f - 1.f)) * mA
         + fabsf(pred_iou[icB] - (iouB * 2.f - 1.f)) * mB;
    mval = mA + mB;
}

__device__ __forceinline__ void block_reduce(float wabs, float mval, double* acc) {
    #pragma unroll
    for (int off = 32; off > 0; off >>= 1) {
        wabs += __shfl_xor(wabs, off);
        mval += __shfl_xor(mval, off);
    }
    __shared__ float sw_[4], sm_[4];
    int lane = threadIdx.x & 63;
    int wid  = threadIdx.x >> 6;
    if (lane == 0) { sw_[wid] = wabs; sm_[wid] = mval; }
    __syncthreads();
    if (threadIdx.x == 0) {
        atomicAdd(&acc[0], (double)(sw_[0] + sw_[1] + sw_[2] + sw_[3]));
        atomicAdd(&acc[1], (double)(sm_[0] + sm_[1] + sm_[2] + sm_[3]));
    }
}

__global__ void __launch_bounds__(256, 2) iou3d_main(
    const float* __restrict__ pred_iou,
    const float* __restrict__ pred_boxes,
    const float* __restrict__ gt_boxes,
    const int*   __restrict__ mask,
    double* __restrict__ acc,
    int N)
{
    int tid = blockIdx.x * blockDim.x + threadIdx.x;
    int iA = 2 * tid, iB = 2 * tid + 1;
    int icA = iA < N ? iA : (N - 1);
    int icB = iB < N ? iB : (N - 1);
    float mA = (iA < N) ? (float)mask[icA] : 0.f;
    float mB = (iB < N) ? (float)mask[icB] : 0.f;

    float wabs, mval;
    pair_core(icA, icB, mA, mB, pred_iou, pred_boxes, gt_boxes, wabs, mval);
    block_reduce(wabs, mval, acc);
}

__global__ void __launch_bounds__(64) iou3d_final(const double* __restrict__ acc,
                                                  float* __restrict__ out) {
    if (threadIdx.x == 0 && blockIdx.x == 0) {
        double s  = acc[0];
        double dm = acc[1];
        double denom = dm > 1e-4 ? dm : 1e-4;
        out[0] = (float)(s / denom);   // LOSS_WEIGHT = 1
    }
}

extern "C" void kernel_launch(void* const* d_in, const int* in_sizes, int n_in,
                              void* d_out, int out_size, void* d_ws, size_t ws_size,
                              hipStream_t stream) {
    const float* pred_iou   = (const float*)d_in[0];
    const float* pred_boxes = (const float*)d_in[1];
    const float* gt_boxes   = (const float*)d_in[2];
    const int*   mask       = (const int*)d_in[3];
    float* out = (float*)d_out;
    double* acc = (double*)d_ws;

    int N = in_sizes[0];
    int blocks = (N + 511) / 512;   // 2 elements per thread

    iou3d_init<<<1, 64, 0, stream>>>(acc);
    iou3d_main<<<blocks, 256, 0, stream>>>(pred_iou, pred_boxes, gt_boxes, mask, acc, N);
    iou3d_final<<<1, 64, 0, stream>>>(acc, out);
}